// Round 8
// baseline (279.188 us; speedup 1.0000x reference)
//
#include <hip/hip_runtime.h>
#include <cstdint>

#define C_ 128
#define L_ 16
#define G_ 4
#define CPG_ 32
#define H_ 56
#define W_ 56
#define HW_ 3136

typedef float f4 __attribute__((ext_vector_type(4)));   // native vec for builtins

// Block = (b, t, g, htile, dy); 256 threads = 8 tx (w-segments of 8) x 32 ty.
// All 7 dx in-register: acc[7][8]. Window r[16] covers value cols [w0-4,w0+12);
// (p,dx) reads r[p+dx+1]. All f4 loads 16B-aligned (spatial pad boundaries
// are multiples of 4 -> each 4-float block fully valid or fully zero, masked).
//
// lds_cap[8192] (32 KiB, address-escaped, never touched): caps occupancy at
// 5 blocks/CU so the register allocator's target drops from 8 waves/EU
// (which squeezes to <=64 VGPR and shuttles acc[7][8] through AGPRs --
// r4/r7 showed VGPR_Count=60 with ~0.9 extra VALU insts per MAC) to 5
// waves/EU (~408-VGPR budget): acc stays in VGPRs, loads stay in flight.
__global__ __launch_bounds__(256, 2)
void wcorr(const float* __restrict__ x, const float* __restrict__ wgt,
           float* __restrict__ out) {
  __shared__ float lds_cap[8192];
  asm volatile("" :: "v"(&lds_cap[threadIdx.x]));   // keep allocation, no traffic

  int bid = blockIdx.x;
  // bijective XCD swizzle: nwg = 7168 = 8 * 896; dy fastest so the 7
  // dy-siblings sharing input rows run adjacently on one XCD's L2.
  int wid = (bid & 7) * 896 + (bid >> 3);
  int dy = wid % 7;
  int rest = wid / 7;              // ((b*16 + t)*4 + g)*2 + htile
  int htile = rest & 1; rest >>= 1;
  int g = rest & 3;     rest >>= 2;
  int t = rest & 15;
  int b = rest >> 4;

  int tid = threadIdx.x;
  int tx = tid & 7;                // 0..7 (tx==7 compute-duplicated, store-masked)
  int ty = tid >> 3;               // 0..31
  int h = htile * 32 + ty;
  if (h >= H_) return;             // whole-wave exit (htile=1, wave 3)

  bool wr = (tx < 7);
  int w0 = wr ? tx * 8 : 48;       // clamp idle lanes to a safe segment
  int hh = h + dy - 3;
  bool hv = (hh >= 0) && (hh < H_);
  int hhs = hv ? hh : 0;
  int t1 = (t > 0) ? (t - 1) : 0;

  // validity of the four 4-col blocks at value cols w0-4, w0, w0+4, w0+8
  bool m0 = hv && (w0 >= 4);
  bool m1 = hv;
  bool m2 = hv;                    // w0+4 <= 52 always in-bounds
  bool m3 = hv && (w0 + 8 < W_);

  const size_t cstride = (size_t)L_ * HW_;
  const float* xbase = x + ((size_t)b * C_ + (size_t)g * CPG_) * cstride;
  const float* xs0 = xbase + (size_t)t * HW_ + (size_t)hhs * W_ + (w0 - 4);
  const float* x10 = xbase + (size_t)t1 * HW_ + (size_t)h * W_ + w0;
  const float* wg0 = wgt + (size_t)(g * CPG_) * (L_ * 49) + t * 49 + dy * 7;

  float acc[7][8];
  #pragma unroll
  for (int i = 0; i < 7; ++i)
    #pragma unroll
    for (int p = 0; p < 8; ++p) acc[i][p] = 0.0f;

  const float sc = 1.0f / 32.0f;

  #pragma unroll 2
  for (int c = 0; c < CPG_; ++c) {
    // issue all global loads first, then the (wave-uniform -> s_load) weights
    const float* xs = xs0 + (size_t)c * cstride;
    const float* x1p = x10 + (size_t)c * cstride;
    f4 q0 = (f4)(0.0f);
    f4 q1 = q0, q2 = q0, q3 = q0;
    if (m0) q0 = *(const f4*)(xs);
    if (m1) q1 = *(const f4*)(xs + 4);
    if (m2) q2 = *(const f4*)(xs + 8);
    if (m3) q3 = *(const f4*)(xs + 12);
    f4 a0 = *(const f4*)(x1p);
    f4 a1 = *(const f4*)(x1p + 4);

    const float* wp = wg0 + (size_t)c * (L_ * 49);
    float w7[7];
    #pragma unroll
    for (int d = 0; d < 7; ++d) w7[d] = wp[d] * sc;   // fold 1/32 here

    float r[16] = {q0.x, q0.y, q0.z, q0.w, q1.x, q1.y, q1.z, q1.w,
                   q2.x, q2.y, q2.z, q2.w, q3.x, q3.y, q3.z, q3.w};
    float x1v[8] = {a0.x, a0.y, a0.z, a0.w, a1.x, a1.y, a1.z, a1.w};

    // output position w0+p, offset dx reads value col (w0+p)+dx-3 -> r[p+dx+1]
    #pragma unroll
    for (int dxx = 0; dxx < 7; ++dxx) {
      #pragma unroll
      for (int p = 0; p < 8; ++p) {
        acc[dxx][p] = fmaf(w7[dxx], x1v[p] * r[p + dxx + 1], acc[dxx][p]);
      }
    }
  }

  if (wr) {
    #pragma unroll
    for (int dxx = 0; dxx < 7; ++dxx) {
      int och = (dy * 7 + dxx) * G_ + g;
      float* op = out + (((size_t)b * 196 + och) * L_ + t) * (size_t)HW_
                      + (size_t)h * W_ + w0;
      f4 o0 = {acc[dxx][0], acc[dxx][1], acc[dxx][2], acc[dxx][3]};
      f4 o1 = {acc[dxx][4], acc[dxx][5], acc[dxx][6], acc[dxx][7]};
      __builtin_nontemporal_store(o0, (f4*)op);        // streaming output:
      __builtin_nontemporal_store(o1, (f4*)(op + 4));  // don't evict x in L2
    }
  }
}

extern "C" void kernel_launch(void* const* d_in, const int* in_sizes, int n_in,
                              void* d_out, int out_size, void* d_ws, size_t ws_size,
                              hipStream_t stream) {
  const float* x = (const float*)d_in[0];
  const float* w = (const float*)d_in[1];
  float* o = (float*)d_out;
  dim3 grid(7168), block(256);
  hipLaunchKernelGGL(wcorr, grid, block, 0, stream, x, w, o);
}

// Round 9
// 229.081 us; speedup vs baseline: 1.2187x; 1.2187x over previous
//
#include <hip/hip_runtime.h>
#include <cstdint>

#define C_ 128
#define L_ 16
#define G_ 4
#define H_ 56
#define W_ 56
#define HW_ 3136
#define CH_ 4                    // channels per chunk
#define NCK_ 8                   // chunks (32 / CH_)
#define RS_ 64                   // LDS row stride (floats)
#define WSZ_ (32 * 49)           // weights: 1568 floats
#define XS_SZ (CH_ * 10 * RS_)   // 2560 floats (10-row halo tile per channel)
#define X1_SZ (CH_ * 4 * RS_)    // 1024 floats
#define BUF_SZ (XS_SZ + X1_SZ)   // 3584
#define LDS_F (WSZ_ + 2 * BUF_SZ)// 8736 floats = 34944 B -> 4 blocks/CU

typedef float f4 __attribute__((ext_vector_type(4)));
typedef __attribute__((address_space(3))) uint32_t lds_u32;
typedef const __attribute__((address_space(1))) uint32_t glb_u32;

// Block = (b, t, g, htile of 4 rows) computing ALL 49 (dy,dx) offsets.
// 256 thr = 8 tx (w-seg of 8; tx==7 idle) x 4 h x 8 dy-slots (dy==7 idle).
// x rows staged ONCE per block into LDS (7x L2-read-traffic cut vs r7's
// dy-per-block). xs tile: 10 halo rows x 64 cols per channel, value col
// cc = w+4 (blocks 1..14 valid); x1 tile: 4 rows x 64 (blocks 0..13 valid).
// XOR swizzle: storage_block = value_block ^ (row&7) [xs] / ^(h&3) [x1],
// applied BOTH at stage (pre-swizzled global source, linear LDS dest as
// global_load_lds requires) and at ds_read. Zero-init covers pad/OOB slots
// (never overwritten -> persists across chunks/buffers).
__global__ __launch_bounds__(256, 2)
void wcorr(const float* __restrict__ x, const float* __restrict__ wgt,
           float* __restrict__ out) {
  __shared__ float lds[LDS_F];

  int bid = blockIdx.x;
  // bijective XCD swizzle: nwg = 7168 = 8*896; htile fastest (halo-row reuse),
  // then t (x[t] re-read as x1 by t+1), then g,b: one (b,g) stays on one XCD.
  int wid = (bid & 7) * 896 + (bid >> 3);
  int htile = wid % 14;
  int rest = wid / 14;             // (b*4+g)*16 + t
  int t = rest & 15;
  int bg = rest >> 4;
  int g = bg & 3;
  int b = bg >> 2;
  int h0 = htile * 4;

  int tid = threadIdx.x;
  int tx = tid & 7;
  int slot = tid >> 3;
  int h = slot & 3;
  int dy = slot >> 2;              // 0..7 (7 = idle)
  bool active = (dy < 7) && (tx < 7);
  int dyc = dy < 7 ? dy : 6;       // clamp idle lanes to safe addresses
  int txc = tx < 7 ? tx : 6;
  int rr = h + dyc;                // xs local row 0..9 (global hh = h0-3+rr)
  int t1 = t > 0 ? t - 1 : 0;

  for (int i = tid; i < LDS_F; i += 256) lds[i] = 0.0f;
  __syncthreads();

  const size_t cstride = (size_t)L_ * HW_;
  const float* xg = x + ((size_t)b * C_ + (size_t)g * 32) * cstride;

  // ---- stage weights once (1/32 folded) ----
  {
    const float sc = 1.0f / 32.0f;
    const float* wsrc = wgt + (size_t)(g * 32) * (L_ * 49) + t * 49;
    #pragma unroll
    for (int j = 0; j < 7; ++j) {
      int idx = tid + j * 256;
      if (idx < WSZ_) {
        int c = idx / 49;
        int i = idx - c * 49;
        lds[idx] = wsrc[(size_t)c * (L_ * 49) + i] * sc;
      }
    }
  }

  // ---- staging helpers (global_load_lds: linear LDS dest = uniform+lane*16,
  //      swizzle realized by pre-swizzling the per-lane GLOBAL source) ----
  auto stage_xs = [&](int tau, int xs_f0, int c0) {  // tau in [0,640)
    int rho = tau >> 4;            // row 0..39: ci = rho/10, r = rho%10
    int sb = tau & 15;             // storage block
    int ci = rho / 10;
    int r = rho - ci * 10;
    int vb = sb ^ (r & 7);         // value block; covers w = vb*4-4 .. +3
    int hh = h0 - 3 + r;
    bool ok = (vb >= 1) && (vb <= 14) && (hh >= 0) && (hh < H_);
    const float* src = xg + (size_t)(c0 + ci) * cstride + (size_t)t * HW_
                          + hh * W_ + (vb * 4 - 4);
    float* dst = &lds[xs_f0 + (tau & ~63) * 4];   // wave-uniform base
    if (ok)
      __builtin_amdgcn_global_load_lds((glb_u32*)src, (lds_u32*)dst, 16, 0, 0);
  };
  auto stage_x1 = [&](int tau, int x1_f0, int c0) {  // tau in [0,256)
    int rho = tau >> 4;            // ci = rho>>2, hx = rho&3
    int sb = tau & 15;
    int ci = rho >> 2;
    int hx = rho & 3;
    int vb = sb ^ hx;              // covers w = vb*4 .. +3
    bool ok = (vb <= 13);
    const float* src = xg + (size_t)(c0 + ci) * cstride + (size_t)t1 * HW_
                          + (h0 + hx) * W_ + vb * 4;
    float* dst = &lds[x1_f0 + (tau & ~63) * 4];
    if (ok)
      __builtin_amdgcn_global_load_lds((glb_u32*)src, (lds_u32*)dst, 16, 0, 0);
  };
  auto stage_chunk = [&](int k) {
    int c0 = k * CH_;
    int xs_f0 = WSZ_ + (k & 1) * BUF_SZ;
    int x1_f0 = xs_f0 + XS_SZ;
    stage_xs(tid, xs_f0, c0);            // xs tasks 0..255
    stage_xs(tid + 256, xs_f0, c0);      // 256..511
    if (tid < 128) {                     // wave-uniform split
      stage_xs(tid + 512, xs_f0, c0);    // 512..639
      stage_x1(tid + 128, x1_f0, c0);    // x1 128..255
    } else {
      stage_x1(tid - 128, x1_f0, c0);    // x1 0..127
    }
  };

  float acc[7][8];
  #pragma unroll
  for (int i = 0; i < 7; ++i)
    #pragma unroll
    for (int p = 0; p < 8; ++p) acc[i][p] = 0.0f;

  int wb0 = 2 * txc;
  int sA = rr & 7;                 // xs row swizzle
  int sB = h;                      // x1 row swizzle (h&3)

  stage_chunk(0);
  __syncthreads();                 // drains vmcnt(0): chunk 0 + weights ready

  #pragma unroll 2
  for (int k = 0; k < NCK_; ++k) {
    if (k + 1 < NCK_) stage_chunk(k + 1);   // issue-early: flies during compute
    int xs_f0 = WSZ_ + (k & 1) * BUF_SZ;
    int x1_f0 = xs_f0 + XS_SZ;
    int c0 = k * CH_;
    #pragma unroll
    for (int ci = 0; ci < CH_; ++ci) {
      const f4* xsrow = (const f4*)&lds[xs_f0 + (ci * 10 + rr) * RS_];
      const f4* x1row = (const f4*)&lds[x1_f0 + (ci * 4 + h) * RS_];
      f4 q0 = xsrow[(wb0 + 0) ^ sA];
      f4 q1 = xsrow[(wb0 + 1) ^ sA];
      f4 q2 = xsrow[(wb0 + 2) ^ sA];
      f4 q3 = xsrow[(wb0 + 3) ^ sA];
      f4 a0 = x1row[(wb0 + 0) ^ sB];
      f4 a1 = x1row[(wb0 + 1) ^ sB];
      const float* wl = &lds[(c0 + ci) * 49 + dyc * 7];
      float w7[7];
      #pragma unroll
      for (int d = 0; d < 7; ++d) w7[d] = wl[d];
      float r[16] = {q0.x, q0.y, q0.z, q0.w, q1.x, q1.y, q1.z, q1.w,
                     q2.x, q2.y, q2.z, q2.w, q3.x, q3.y, q3.z, q3.w};
      float x1v[8] = {a0.x, a0.y, a0.z, a0.w, a1.x, a1.y, a1.z, a1.w};
      #pragma unroll
      for (int dxx = 0; dxx < 7; ++dxx) {
        #pragma unroll
        for (int p = 0; p < 8; ++p) {
          acc[dxx][p] = fmaf(w7[dxx], x1v[p] * r[p + dxx + 1], acc[dxx][p]);
        }
      }
    }
    __syncthreads();   // compute(k) done; stage(k+1) drained (vmcnt0 at barrier)
  }

  if (active) {
    int w0 = tx * 8;
    #pragma unroll
    for (int dxx = 0; dxx < 7; ++dxx) {
      int och = (dy * 7 + dxx) * G_ + g;
      float* op = out + (((size_t)b * 196 + och) * L_ + t) * (size_t)HW_
                      + (size_t)(h0 + h) * W_ + w0;
      f4 o0 = {acc[dxx][0], acc[dxx][1], acc[dxx][2], acc[dxx][3]};
      f4 o1 = {acc[dxx][4], acc[dxx][5], acc[dxx][6], acc[dxx][7]};
      __builtin_nontemporal_store(o0, (f4*)op);
      __builtin_nontemporal_store(o1, (f4*)(op + 4));
    }
  }
}

extern "C" void kernel_launch(void* const* d_in, const int* in_sizes, int n_in,
                              void* d_out, int out_size, void* d_ws, size_t ws_size,
                              hipStream_t stream) {
  const float* x = (const float*)d_in[0];
  const float* w = (const float*)d_in[1];
  float* o = (float*)d_out;
  dim3 grid(7168), block(256);
  hipLaunchKernelGGL(wcorr, grid, block, 0, stream, x, w, o);
}